// Round 4
// baseline (1042.882 us; speedup 1.0000x reference)
//
#include <hip/hip_runtime.h>

// x[16,4096,512] fp32 -> windows [1024, 64, 512]
//   qkv = xw @ Wqkv[512,1536]; per head (8 x 64d): S = QK^T/8, causal mask,
//   softmax, softmax AGAIN (no re-mask), out = P2 @ V; concat; @ Wproj + bproj.
// Split pipeline: prep_weights + prep_x -> attn_core -> proj_gemm.

typedef _Float16 f16x8 __attribute__((ext_vector_type(8)));
typedef float f32x4 __attribute__((ext_vector_type(4)));

#define MFMA16(a, b, c) __builtin_amdgcn_mfma_f32_16x16x32_f16((a), (b), (c), 0, 0, 0)

__device__ __forceinline__ int swz64(int r, int c) { return r * 64 + (c ^ ((r & 7) << 3)); }
__device__ __forceinline__ int swz512(int r, int c) { return r * 512 + (c ^ ((r & 7) << 3)); }

// ---------------------------------------------------------------------------
// Prep: fp32 weights -> fp16 MFMA B-fragment packed layout.
//   packed[r16][kt][lane][e] = W^T(r16*16 + (lane&15), kt*32 + (lane>>4)*8 + e)
// ---------------------------------------------------------------------------
__global__ void prep_weights(const float* __restrict__ Wqkv,
                             const float* __restrict__ Wproj,
                             _Float16* __restrict__ wqkvP,
                             _Float16* __restrict__ wprojP) {
  int idx = blockIdx.x * blockDim.x + threadIdx.x;
  if (idx < 786432) {
    int r16 = idx >> 13;
    int rem = idx & 8191;
    int kt = rem >> 9;
    int lane = (rem >> 3) & 63;
    int e = rem & 7;
    int row = r16 * 16 + (lane & 15);
    int k = kt * 32 + (lane >> 4) * 8 + e;
    float v = Wqkv[k * 1536 + row];
    if (row < 512) v *= 0.125f;  // fold hd^-0.5 into Q
    wqkvP[idx] = (_Float16)v;
  } else {
    int j = idx - 786432;
    int r16 = j >> 13;
    int rem = j & 8191;
    int kt = rem >> 9;
    int lane = (rem >> 3) & 63;
    int e = rem & 7;
    int n = r16 * 16 + (lane & 15);
    int k = kt * 32 + (lane >> 4) * 8 + e;
    wprojP[j] = (_Float16)Wproj[k * 512 + n];
  }
}

// ---------------------------------------------------------------------------
// Prep: x fp32 -> fp16 MFMA A-fragment packed layout per window.
//   xP[w][rt][ks][lane][e] = x[w*64 + rt*16 + (lane&15)][ks*32 + (lane>>4)*8 + e]
// ---------------------------------------------------------------------------
__global__ __launch_bounds__(512) void prep_x(const float* __restrict__ x,
                                              _Float16* __restrict__ xP) {
  __shared__ __align__(16) _Float16 sX[64 * 512];
  const int tid = threadIdx.x;
  const float4* xv = (const float4*)(x + (size_t)blockIdx.x * 32768);
#pragma unroll
  for (int it = 0; it < 8; ++it) {
    int g = tid + it * 512;
    int r = g >> 6, c0 = (g & 63) << 3;
    float4 a = xv[(r << 7) + (c0 >> 2)];
    float4 b = xv[(r << 7) + (c0 >> 2) + 1];
    f16x8 hv;
    hv[0] = (_Float16)a.x; hv[1] = (_Float16)a.y;
    hv[2] = (_Float16)a.z; hv[3] = (_Float16)a.w;
    hv[4] = (_Float16)b.x; hv[5] = (_Float16)b.y;
    hv[6] = (_Float16)b.z; hv[7] = (_Float16)b.w;
    *(f16x8*)&sX[swz512(r, c0)] = hv;
  }
  __syncthreads();
  _Float16* dst = xP + (size_t)blockIdx.x * 32768;
#pragma unroll
  for (int it = 0; it < 8; ++it) {
    int c8 = tid + it * 512;
    int rt = c8 >> 10, ks = (c8 >> 6) & 15, ln = c8 & 63;
    int row = rt * 16 + (ln & 15);
    int k0 = ks * 32 + (ln >> 4) * 8;
    f16x8 v = *(const f16x8*)&sX[swz512(row, k0)];
    *(f16x8*)(dst + c8 * 8) = v;
  }
}

// ---------------------------------------------------------------------------
// attn_core: QKV projection + double-softmax attention per window.
// 1 block = 1 window, 512 threads, LDS 64 KB -> 2 blocks/CU, 4 waves/SIMD.
// Writes head outputs in A-fragment packed fp16 layout (same scheme as xP).
// ---------------------------------------------------------------------------
__global__ __launch_bounds__(512, 4) void attn_core(
    const _Float16* __restrict__ xP, const _Float16* __restrict__ wqkvP,
    _Float16* __restrict__ hP) {
  __shared__ __align__(16) _Float16 sHeads[4][2][4096];  // Q,K,VT,PO x 2 heads

  const int tid = threadIdx.x;
  const int wid = tid >> 6;
  const int lane = tid & 63;
  const int lg = lane >> 4;
  const int lr = lane & 15;

  _Float16* sQb = &sHeads[0][0][0];
  _Float16* sKb = &sHeads[1][0][0];
  _Float16* sVb = &sHeads[2][0][0];
  _Float16* sPb = &sHeads[3][0][0];

  const _Float16* xb = xP + (size_t)blockIdx.x * 32768 + lane * 8;
  _Float16* hb = hP + (size_t)blockIdx.x * 32768 + lane * 8;
  const f32x4 zero4 = {0.f, 0.f, 0.f, 0.f};

  for (int hp = 0; hp < 4; ++hp) {
    // ===== Phase A: QKV col-strips. 24 units (hh, sec, strip), 3 per wave ===
    int hu[3], su[3], stu[3];
    const _Float16* bp[3];
    f32x4 acc[3][4];
#pragma unroll
    for (int i = 0; i < 3; ++i) {
      int u = wid + 8 * i;
      int hh = u & 1, v2 = u >> 1;
      int sec = v2 % 3, strip = v2 / 3;
      hu[i] = hh; su[i] = sec; stu[i] = strip;
      int r16 = sec * 32 + (hp * 2 + hh) * 4 + strip;
      bp[i] = wqkvP + (size_t)r16 * 8192 + lane * 8;
#pragma unroll
      for (int rt = 0; rt < 4; ++rt) acc[i][rt] = zero4;
    }
    f16x8 af[2][4], bf[2][3];
#pragma unroll
    for (int rt = 0; rt < 4; ++rt) af[0][rt] = *(const f16x8*)(xb + rt * 8192);
#pragma unroll
    for (int i = 0; i < 3; ++i) bf[0][i] = *(const f16x8*)bp[i];
#pragma unroll
    for (int ks = 0; ks < 16; ++ks) {
      int cur = ks & 1, nxt = cur ^ 1;
      if (ks < 15) {
#pragma unroll
        for (int rt = 0; rt < 4; ++rt)
          af[nxt][rt] = *(const f16x8*)(xb + rt * 8192 + (ks + 1) * 512);
#pragma unroll
        for (int i = 0; i < 3; ++i)
          bf[nxt][i] = *(const f16x8*)(bp[i] + (ks + 1) * 512);
      }
#pragma unroll
      for (int i = 0; i < 3; ++i)
#pragma unroll
        for (int rt = 0; rt < 4; ++rt)
          acc[i][rt] = MFMA16(af[cur][rt], bf[cur][i], acc[i][rt]);
    }
    // scatter to LDS
#pragma unroll
    for (int i = 0; i < 3; ++i) {
      int hh = hu[i], sec = su[i], strip = stu[i];
      _Float16* dq = sQb + hh * 4096;
      _Float16* dk = sKb + hh * 4096;
      _Float16* dv = sVb + hh * 4096;
#pragma unroll
      for (int rt = 0; rt < 4; ++rt)
#pragma unroll
        for (int rg = 0; rg < 4; ++rg) {
          int row = rt * 16 + lg * 4 + rg;
          int col = strip * 16 + lr;
          _Float16 v = (_Float16)acc[i][rt][rg];
          if (sec == 0) dq[swz64(row, col)] = v;
          else if (sec == 1) dk[swz64(row, col)] = v;
          else dv[swz64(col, row)] = v;  // V transposed
        }
    }
    __syncthreads();  // barrier 1: Q/K/V ready

    // ===== Phase B: S = QK^T, double softmax, PV (row-strips) ==============
    {
      const int hh = wid >> 2;
      const int rs = wid & 3;
      const _Float16* mQ = sQb + hh * 4096;
      const _Float16* mK = sKb + hh * 4096;
      const _Float16* mV = sVb + hh * 4096;
      _Float16* mP = sPb + hh * 4096;
      f32x4 sacc[4];
#pragma unroll
      for (int nt = 0; nt < 4; ++nt) sacc[nt] = zero4;
#pragma unroll
      for (int ks = 0; ks < 2; ++ks) {
        f16x8 afq = *(const f16x8*)&mQ[swz64(rs * 16 + lr, ks * 32 + lg * 8)];
#pragma unroll
        for (int nt = 0; nt < 4; ++nt) {
          f16x8 bfk = *(const f16x8*)&mK[swz64(nt * 16 + lr, ks * 32 + lg * 8)];
          sacc[nt] = MFMA16(afq, bfk, sacc[nt]);
        }
      }
      float p2[4][4];
#pragma unroll
      for (int rg = 0; rg < 4; ++rg) {
        int row = rs * 16 + lg * 4 + rg;
        float m = -1e30f;
#pragma unroll
        for (int nt = 0; nt < 4; ++nt) {
          int col = nt * 16 + lr;
          float v = (col <= row) ? sacc[nt][rg] : -1e30f;
          m = fmaxf(m, v);
        }
#pragma unroll
        for (int off = 8; off >= 1; off >>= 1) m = fmaxf(m, __shfl_xor(m, off));
        float e[4], s1 = 0.f;
#pragma unroll
        for (int nt = 0; nt < 4; ++nt) {
          int col = nt * 16 + lr;
          e[nt] = (col <= row) ? __expf(sacc[nt][rg] - m) : 0.f;
          s1 += e[nt];
        }
#pragma unroll
        for (int off = 8; off >= 1; off >>= 1) s1 += __shfl_xor(s1, off);
        float inv1 = 1.f / s1;
        float e2[4], s2 = 0.f;
#pragma unroll
        for (int nt = 0; nt < 4; ++nt) {
          e2[nt] = __expf(e[nt] * inv1);
          s2 += e2[nt];
        }
#pragma unroll
        for (int off = 8; off >= 1; off >>= 1) s2 += __shfl_xor(s2, off);
        float inv2 = 1.f / s2;
#pragma unroll
        for (int nt = 0; nt < 4; ++nt) p2[nt][rg] = e2[nt] * inv2;
      }
#pragma unroll
      for (int nt = 0; nt < 4; ++nt)
#pragma unroll
        for (int rg = 0; rg < 4; ++rg)
          mP[swz64(rs * 16 + lg * 4 + rg, nt * 16 + lr)] = (_Float16)p2[nt][rg];
      asm volatile("" ::: "memory");
      f32x4 oacc[4];
#pragma unroll
      for (int nt = 0; nt < 4; ++nt) oacc[nt] = zero4;
#pragma unroll
      for (int ks = 0; ks < 2; ++ks) {
        f16x8 afp = *(const f16x8*)&mP[swz64(rs * 16 + lr, ks * 32 + lg * 8)];
#pragma unroll
        for (int nt = 0; nt < 4; ++nt) {
          f16x8 bfv = *(const f16x8*)&mV[swz64(nt * 16 + lr, ks * 32 + lg * 8)];
          oacc[nt] = MFMA16(afp, bfv, oacc[nt]);
        }
      }
      asm volatile("" ::: "memory");
#pragma unroll
      for (int nt = 0; nt < 4; ++nt)
#pragma unroll
        for (int rg = 0; rg < 4; ++rg)
          mP[swz64(rs * 16 + lg * 4 + rg, nt * 16 + lr)] = (_Float16)oacc[nt][rg];
    }
    __syncthreads();  // barrier 2: head outputs ready in sPO

    // ===== epilogue: write head outputs packed (A-fragment layout) =========
#pragma unroll
    for (int j = 0; j < 2; ++j) {
      int c = wid * 2 + j;              // 16 chunks: rt(4) x ksl(4)
      int rt = c >> 2, ksl = c & 3;
      int k0 = ksl * 32 + lg * 8;       // k within the 128-wide head-pair slice
      int hh = k0 >> 6, d0 = k0 & 63;
      int row = rt * 16 + lr;
      const _Float16* src = sPb + hh * 4096;
      f16x8 v = *(const f16x8*)&src[swz64(row, d0)];
      *(f16x8*)(hb + rt * 8192 + (hp * 4 + ksl) * 512) = v;
    }
    // no barrier: next phase A writes sQ/sK/sVT (readers done at barrier 2);
    // sPO is next written in phase B only after its barrier 1.
  }
}

// ---------------------------------------------------------------------------
// proj_gemm: out[65536,512] = hOut[65536,512](packed fp16) @ WprojP + bias.
// 256 threads (4 waves), tile 32 rows x 256 cols, wave = 32x64.
// ---------------------------------------------------------------------------
__global__ __launch_bounds__(256, 4) void proj_gemm(
    const _Float16* __restrict__ hP, const _Float16* __restrict__ wprojP,
    const float* __restrict__ bproj, float* __restrict__ out) {
  __shared__ __align__(16) float sEp[32 * 260];
  const int tid = threadIdx.x;
  const int wq = tid >> 6;
  const int lane = tid & 63;
  const int lg = lane >> 4;
  const int lr = lane & 15;

  int rb = (blockIdx.x >> 1) * 32;
  int cb = (blockIdx.x & 1) * 256;
  int w = rb >> 6, rh = (rb >> 5) & 1;
  const _Float16* ab = hP + (size_t)w * 32768 + (size_t)rh * 16384 + lane * 8;
  const _Float16* bb = wprojP + (size_t)((cb >> 4) + wq * 4) * 8192 + lane * 8;

  const f32x4 zero4 = {0.f, 0.f, 0.f, 0.f};
  f32x4 acc[2][4];
#pragma unroll
  for (int rt = 0; rt < 2; ++rt)
#pragma unroll
    for (int nt = 0; nt < 4; ++nt) acc[rt][nt] = zero4;

  f16x8 af[2][2], bf[2][4];
#pragma unroll
  for (int rt = 0; rt < 2; ++rt) af[0][rt] = *(const f16x8*)(ab + rt * 8192);
#pragma unroll
  for (int nt = 0; nt < 4; ++nt) bf[0][nt] = *(const f16x8*)(bb + nt * 8192);
#pragma unroll
  for (int ks = 0; ks < 16; ++ks) {
    int cur = ks & 1, nxt = cur ^ 1;
    if (ks < 15) {
#pragma unroll
      for (int rt = 0; rt < 2; ++rt)
        af[nxt][rt] = *(const f16x8*)(ab + rt * 8192 + (ks + 1) * 512);
#pragma unroll
      for (int nt = 0; nt < 4; ++nt)
        bf[nxt][nt] = *(const f16x8*)(bb + nt * 8192 + (ks + 1) * 512);
    }
#pragma unroll
    for (int nt = 0; nt < 4; ++nt)
#pragma unroll
      for (int rt = 0; rt < 2; ++rt)
        acc[rt][nt] = MFMA16(af[cur][rt], bf[cur][nt], acc[rt][nt]);
  }
  // epilogue: LDS stage (stride 260 floats: row step 4 -> +16 banks, clean)
#pragma unroll
  for (int rt = 0; rt < 2; ++rt)
#pragma unroll
    for (int nt = 0; nt < 4; ++nt)
#pragma unroll
      for (int rg = 0; rg < 4; ++rg) {
        int row = rt * 16 + lg * 4 + rg;
        int col = wq * 64 + nt * 16 + lr;
        sEp[row * 260 + col] = acc[rt][nt][rg];
      }
  __syncthreads();
#pragma unroll
  for (int it = 0; it < 8; ++it) {
    int idx = tid + it * 256;
    int row = idx >> 6, c0 = (idx & 63) << 2;
    float4 v = *(const float4*)&sEp[row * 260 + c0];
    float4 b = *(const float4*)&bproj[cb + c0];
    v.x += b.x; v.y += b.y; v.z += b.z; v.w += b.w;
    *(float4*)&out[(size_t)(rb + row) * 512 + cb + c0] = v;
  }
}

// ---------------------------------------------------------------------------
// Fallback (verified R2 kernel) for small workspaces: fused, 128 KB LDS.
// ---------------------------------------------------------------------------
__global__ __launch_bounds__(512, 2) void attn_fused(
    const float* __restrict__ x, const _Float16* __restrict__ wqkvP,
    const _Float16* __restrict__ wprojP, const float* __restrict__ bproj,
    float* __restrict__ out) {
  __shared__ __align__(16) _Float16 sX[64 * 512];
  __shared__ __align__(16) _Float16 sHeads[4][2][4096];

  const int tid = threadIdx.x;
  const int wid = tid >> 6;
  const int lane = tid & 63;
  const int lg = lane >> 4;
  const int lr = lane & 15;

  _Float16* sQ0 = &sHeads[0][0][0];
  _Float16* sQ1 = &sHeads[0][1][0];
  _Float16* sK0 = &sHeads[1][0][0];
  _Float16* sK1 = &sHeads[1][1][0];
  _Float16* sVT0 = &sHeads[2][0][0];
  _Float16* sVT1 = &sHeads[2][1][0];
  _Float16* sPO0 = &sHeads[3][0][0];
  _Float16* sPO1 = &sHeads[3][1][0];

  const float4* xv = (const float4*)(x + (size_t)blockIdx.x * 32768);
#pragma unroll
  for (int it = 0; it < 8; ++it) {
    int g = tid + it * 512;
    int r = g >> 6, c0 = (g & 63) << 3;
    float4 a = xv[(r << 7) + (c0 >> 2)];
    float4 b = xv[(r << 7) + (c0 >> 2) + 1];
    f16x8 hv;
    hv[0] = (_Float16)a.x; hv[1] = (_Float16)a.y;
    hv[2] = (_Float16)a.z; hv[3] = (_Float16)a.w;
    hv[4] = (_Float16)b.x; hv[5] = (_Float16)b.y;
    hv[6] = (_Float16)b.z; hv[7] = (_Float16)b.w;
    *(f16x8*)&sX[swz512(r, c0)] = hv;
  }
  const f32x4 zero4 = {0.f, 0.f, 0.f, 0.f};
  f32x4 accO[4][4];
#pragma unroll
  for (int i = 0; i < 4; ++i)
#pragma unroll
    for (int j = 0; j < 4; ++j) accO[i][j] = zero4;
  __syncthreads();

  for (int hp = 0; hp < 4; ++hp) {
    int hu[3], su[3], stu[3];
    const _Float16* bp[3];
    f32x4 acc[3][4];
#pragma unroll
    for (int i = 0; i < 3; ++i) {
      int u = wid + 8 * i;
      int hh = u & 1, v2 = u >> 1;
      int sec = v2 % 3, strip = v2 / 3;
      hu[i] = hh; su[i] = sec; stu[i] = strip;
      int r16 = sec * 32 + (hp * 2 + hh) * 4 + strip;
      bp[i] = wqkvP + (size_t)r16 * 8192 + lane * 8;
#pragma unroll
      for (int rt = 0; rt < 4; ++rt) acc[i][rt] = zero4;
    }
    f16x8 bf[3][3];
#pragma unroll
    for (int d = 0; d < 3; ++d)
#pragma unroll
      for (int i = 0; i < 3; ++i) bf[d][i] = *(const f16x8*)(bp[i] + d * 512);
    f16x8 af[2][4];
#pragma unroll
    for (int rt = 0; rt < 4; ++rt)
      af[0][rt] = *(const f16x8*)&sX[swz512(rt * 16 + lr, lg * 8)];
#pragma unroll
    for (int ks = 0; ks < 16; ++ks) {
      if (ks < 15) {
#pragma unroll
        for (int rt = 0; rt < 4; ++rt)
          af[(ks + 1) & 1][rt] =
              *(const f16x8*)&sX[swz512(rt * 16 + lr, (ks + 1) * 32 + lg * 8)];
      }
#pragma unroll
      for (int i = 0; i < 3; ++i)
#pragma unroll
        for (int rt = 0; rt < 4; ++rt)
          acc[i][rt] = MFMA16(af[ks & 1][rt], bf[ks % 3][i], acc[i][rt]);
      if (ks + 3 < 16) {
#pragma unroll
        for (int i = 0; i < 3; ++i)
          bf[ks % 3][i] = *(const f16x8*)(bp[i] + (ks + 3) * 512);
      }
    }
#pragma unroll
    for (int i = 0; i < 3; ++i) {
      int hh = hu[i], sec = su[i], strip = stu[i];
      _Float16* dq = hh ? sQ1 : sQ0;
      _Float16* dk = hh ? sK1 : sK0;
      _Float16* dv = hh ? sVT1 : sVT0;
#pragma unroll
      for (int rt = 0; rt < 4; ++rt)
#pragma unroll
        for (int rg = 0; rg < 4; ++rg) {
          int row = rt * 16 + lg * 4 + rg;
          int col = strip * 16 + lr;
          _Float16 v = (_Float16)acc[i][rt][rg];
          if (sec == 0) dq[swz64(row, col)] = v;
          else if (sec == 1) dk[swz64(row, col)] = v;
          else dv[swz64(col, row)] = v;
        }
    }
    __syncthreads();
    {
      const int hh = wid >> 2;
      const int rs = wid & 3;
      const _Float16* mQ = hh ? sQ1 : sQ0;
      const _Float16* mK = hh ? sK1 : sK0;
      const _Float16* mV = hh ? sVT1 : sVT0;
      _Float16* mP = hh ? sPO1 : sPO0;
      f32x4 sacc[4];
#pragma unroll
      for (int nt = 0; nt < 4; ++nt) sacc[nt] = zero4;
#pragma unroll
      for (int ks = 0; ks < 2; ++ks) {
        f16x8 afq = *(const f16x8*)&mQ[swz64(rs * 16 + lr, ks * 32 + lg * 8)];
#pragma unroll
        for (int nt = 0; nt < 4; ++nt) {
          f16x8 bfk = *(const f16x8*)&mK[swz64(nt * 16 + lr, ks * 32 + lg * 8)];
          sacc[nt] = MFMA16(afq, bfk, sacc[nt]);
        }
      }
      float p2[4][4];
#pragma unroll
      for (int rg = 0; rg < 4; ++rg) {
        int row = rs * 16 + lg * 4 + rg;
        float m = -1e30f;
#pragma unroll
        for (int nt = 0; nt < 4; ++nt) {
          int col = nt * 16 + lr;
          float v = (col <= row) ? sacc[nt][rg] : -1e30f;
          m = fmaxf(m, v);
        }
#pragma unroll
        for (int off = 8; off >= 1; off >>= 1) m = fmaxf(m, __shfl_xor(m, off));
        float e[4], s1 = 0.f;
#pragma unroll
        for (int nt = 0; nt < 4; ++nt) {
          int col = nt * 16 + lr;
          e[nt] = (col <= row) ? __expf(sacc[nt][rg] - m) : 0.f;
          s1 += e[nt];
        }
#pragma unroll
        for (int off = 8; off >= 1; off >>= 1) s1 += __shfl_xor(s1, off);
        float inv1 = 1.f / s1;
        float e2[4], s2 = 0.f;
#pragma unroll
        for (int nt = 0; nt < 4; ++nt) {
          e2[nt] = __expf(e[nt] * inv1);
          s2 += e2[nt];
        }
#pragma unroll
        for (int off = 8; off >= 1; off >>= 1) s2 += __shfl_xor(s2, off);
        float inv2 = 1.f / s2;
#pragma unroll
        for (int nt = 0; nt < 4; ++nt) p2[nt][rg] = e2[nt] * inv2;
      }
#pragma unroll
      for (int nt = 0; nt < 4; ++nt)
#pragma unroll
        for (int rg = 0; rg < 4; ++rg)
          mP[swz64(rs * 16 + lg * 4 + rg, nt * 16 + lr)] = (_Float16)p2[nt][rg];
      asm volatile("" ::: "memory");
      f32x4 oacc[4];
#pragma unroll
      for (int nt = 0; nt < 4; ++nt) oacc[nt] = zero4;
#pragma unroll
      for (int ks = 0; ks < 2; ++ks) {
        f16x8 afp = *(const f16x8*)&mP[swz64(rs * 16 + lr, ks * 32 + lg * 8)];
#pragma unroll
        for (int nt = 0; nt < 4; ++nt) {
          f16x8 bfv = *(const f16x8*)&mV[swz64(nt * 16 + lr, ks * 32 + lg * 8)];
          oacc[nt] = MFMA16(afp, bfv, oacc[nt]);
        }
      }
      asm volatile("" ::: "memory");
#pragma unroll
      for (int nt = 0; nt < 4; ++nt)
#pragma unroll
        for (int rg = 0; rg < 4; ++rg)
          mP[swz64(rs * 16 + lg * 4 + rg, nt * 16 + lr)] = (_Float16)oacc[nt][rg];
    }
    __syncthreads();
    {
      f16x8 bfC[2][4], afC[2][4];
      const _Float16* po[2] = {sPO0, sPO1};
#pragma unroll
      for (int rt = 0; rt < 4; ++rt)
        afC[0][rt] = *(const f16x8*)&po[0][swz64(rt * 16 + lr, lg * 8)];
#pragma unroll
      for (int nt = 0; nt < 4; ++nt)
        bfC[0][nt] = *(const f16x8*)(wprojP + (size_t)(wid * 4 + nt) * 8192 +
                                     (size_t)(hp * 4) * 512 + lane * 8);
#pragma unroll
      for (int g = 0; g < 4; ++g) {
        if (g < 3) {
          int hn = (g + 1) >> 1, kn = (g + 1) & 1;
#pragma unroll
          for (int rt = 0; rt < 4; ++rt)
            afC[(g + 1) & 1][rt] =
                *(const f16x8*)&po[hn][swz64(rt * 16 + lr, kn * 32 + lg * 8)];
#pragma unroll
          for (int nt = 0; nt < 4; ++nt)
            bfC[(g + 1) & 1][nt] =
                *(const f16x8*)(wprojP + (size_t)(wid * 4 + nt) * 8192 +
                                (size_t)(hp * 4 + g + 1) * 512 + lane * 8);
        }
#pragma unroll
        for (int nt = 0; nt < 4; ++nt)
#pragma unroll
          for (int rt = 0; rt < 4; ++rt)
            accO[rt][nt] = MFMA16(afC[g & 1][rt], bfC[g & 1][nt], accO[rt][nt]);
      }
    }
  }
  __syncthreads();
  float bias_r[4];
#pragma unroll
  for (int nt = 0; nt < 4; ++nt) bias_r[nt] = bproj[wid * 64 + nt * 16 + lr];
  float* sEp = (float*)&sHeads[0][0][0];
  size_t base = (size_t)blockIdx.x * 32768;
#pragma unroll
  for (int half = 0; half < 2; ++half) {
#pragma unroll
    for (int rr = 0; rr < 2; ++rr) {
      int rt = half * 2 + rr;
#pragma unroll
      for (int nt = 0; nt < 4; ++nt)
#pragma unroll
        for (int rg = 0; rg < 4; ++rg) {
          int r = rr * 16 + lg * 4 + rg;
          int c = wid * 64 + nt * 16 + lr;
          sEp[r * 512 + (c ^ (((r >> 2) & 1) << 4))] = accO[rt][nt][rg] + bias_r[nt];
        }
    }
    __syncthreads();
#pragma unroll
    for (int j = 0; j < 8; ++j) {
      int f4 = tid + j * 512;
      int r = f4 >> 7;
      int c0 = (f4 & 127) << 2;
      float4 v = *(const float4*)&sEp[r * 512 + (c0 ^ (((r >> 2) & 1) << 4))];
      *(float4*)&out[base + (size_t)(half * 32 + r) * 512 + c0] = v;
    }
    if (half == 0) __syncthreads();
  }
}

extern "C" void kernel_launch(void* const* d_in, const int* in_sizes, int n_in,
                              void* d_out, int out_size, void* d_ws, size_t ws_size,
                              hipStream_t stream) {
  const float* x = (const float*)d_in[0];
  const float* Wqkv = (const float*)d_in[1];
  const float* Wproj = (const float*)d_in[2];
  const float* bproj = (const float*)d_in[3];
  float* out = (float*)d_out;

  _Float16* wqkvP = (_Float16*)d_ws;        // 786432 elems
  _Float16* wprojP = wqkvP + 786432;        // 262144 elems
  _Float16* xPbuf = wprojP + 262144;        // 33554432 elems
  _Float16* hPbuf = xPbuf + 33554432;       // 33554432 elems
  const size_t NEED = (size_t)(786432 + 262144 + 2 * 33554432) * 2;

  prep_weights<<<dim3(4096), dim3(256), 0, stream>>>(Wqkv, Wproj, wqkvP, wprojP);
  if (ws_size >= NEED) {
    prep_x<<<dim3(1024), dim3(512), 0, stream>>>(x, xPbuf);
    attn_core<<<dim3(1024), dim3(512), 0, stream>>>(xPbuf, wqkvP, hPbuf);
    proj_gemm<<<dim3(4096), dim3(256), 0, stream>>>(hPbuf, wprojP, bproj, out);
  } else {
    attn_fused<<<dim3(1024), dim3(512), 0, stream>>>(x, wqkvP, wprojP, bproj, out);
  }
}

// Round 5
// 312.758 us; speedup vs baseline: 3.3345x; 3.3345x over previous
//
#include <hip/hip_runtime.h>

// x[16,4096,512] fp32 -> windows [1024, 64, 512]
//   qkv = xw @ Wqkv[512,1536]; per head (8 x 64d): S = QK^T/8, causal mask,
//   softmax, softmax AGAIN (no re-mask), out = P2 @ V; concat; @ Wproj + bproj.
//
// Pipeline: prep_weights, prep_x (pack fp16 fragments) ->
//   gemmT<0>: qkv' Q/K cols (transposed orientation, A=Wqkv^T rows, B=x rows)
//   gemmT<1>: qkv  V cols  (normal orientation)      -> qkvP packed per (w,h)
//   attn_win: per-window double-softmax attention    -> hP packed
//   gemmT<2>: out^T = Wproj^T @ hOut^T + bias        -> out fp32 row-major
//
// FP(R) packing of M[r][k], k in [0,512):
//   pos(r,k) = ((r>>4)*16 + (k>>5))*512 + (((k>>3)&3)*16 + (r&15))*8 + (k&7)
// == MFMA 16x16x32 fragment order: chunk(strip,kt) is 1KB, lane*8 linear.

typedef _Float16 f16x8 __attribute__((ext_vector_type(8)));
typedef _Float16 f16x4 __attribute__((ext_vector_type(4)));
typedef float f32x4 __attribute__((ext_vector_type(4)));

#define MFMA16(a, b, c) __builtin_amdgcn_mfma_f32_16x16x32_f16((a), (b), (c), 0, 0, 0)

__device__ __forceinline__ int swz64(int r, int c) { return r * 64 + (c ^ ((r & 7) << 3)); }
__device__ __forceinline__ int swz512(int r, int c) { return r * 512 + (c ^ ((r & 7) << 3)); }

typedef const __attribute__((address_space(1))) void* gas1_t;
typedef __attribute__((address_space(3))) void* las3_t;

// async global->LDS, 16B per lane; LDS dest = wave-uniform base + lane*16
__device__ __forceinline__ void stage16(const _Float16* g, _Float16* lbase, int lane) {
#if __has_builtin(__builtin_amdgcn_global_load_lds)
  __builtin_amdgcn_global_load_lds((gas1_t)(const void*)g, (las3_t)(void*)lbase, 16, 0, 0);
#else
  *(f16x8*)(lbase + lane * 8) = *(const f16x8*)g;
#endif
}

// ---------------------------------------------------------------------------
// prep_weights: wqkvP = FP(Wqkv^T, 1536 rows) with Q rows scaled by 0.125;
//               wprojP = FP(Wproj^T, 512 rows).
// ---------------------------------------------------------------------------
__global__ void prep_weights(const float* __restrict__ Wqkv,
                             const float* __restrict__ Wproj,
                             _Float16* __restrict__ wqkvP,
                             _Float16* __restrict__ wprojP) {
  int idx = blockIdx.x * blockDim.x + threadIdx.x;
  if (idx < 786432) {
    int r16 = idx >> 13;
    int rem = idx & 8191;
    int kt = rem >> 9;
    int lane = (rem >> 3) & 63;
    int e = rem & 7;
    int row = r16 * 16 + (lane & 15);
    int k = kt * 32 + (lane >> 4) * 8 + e;
    float v = Wqkv[k * 1536 + row];
    if (row < 512) v *= 0.125f;
    wqkvP[idx] = (_Float16)v;
  } else {
    int j = idx - 786432;
    int r16 = j >> 13;
    int rem = j & 8191;
    int kt = rem >> 9;
    int lane = (rem >> 3) & 63;
    int e = rem & 7;
    int n = r16 * 16 + (lane & 15);
    int k = kt * 32 + (lane >> 4) * 8 + e;
    wprojP[j] = (_Float16)Wproj[k * 512 + n];
  }
}

// ---------------------------------------------------------------------------
// prep_x: xP = FP(x fp16, 65536 rows)
// ---------------------------------------------------------------------------
__global__ __launch_bounds__(512) void prep_x(const float* __restrict__ x,
                                              _Float16* __restrict__ xP) {
  __shared__ __align__(16) _Float16 sX[64 * 512];
  const int tid = threadIdx.x;
  const float4* xv = (const float4*)(x + (size_t)blockIdx.x * 32768);
#pragma unroll
  for (int it = 0; it < 8; ++it) {
    int g = tid + it * 512;
    int r = g >> 6, c0 = (g & 63) << 3;
    float4 a = xv[(r << 7) + (c0 >> 2)];
    float4 b = xv[(r << 7) + (c0 >> 2) + 1];
    f16x8 hv;
    hv[0] = (_Float16)a.x; hv[1] = (_Float16)a.y;
    hv[2] = (_Float16)a.z; hv[3] = (_Float16)a.w;
    hv[4] = (_Float16)b.x; hv[5] = (_Float16)b.y;
    hv[6] = (_Float16)b.z; hv[7] = (_Float16)b.w;
    *(f16x8*)&sX[swz512(r, c0)] = hv;
  }
  __syncthreads();
  _Float16* dst = xP + (size_t)blockIdx.x * 32768;
#pragma unroll
  for (int it = 0; it < 8; ++it) {
    int c8 = tid + it * 512;
    int rt = c8 >> 10, ks = (c8 >> 6) & 15, ln = c8 & 63;
    int row = rt * 16 + (ln & 15);
    int k0 = ks * 32 + (ln >> 4) * 8;
    f16x8 v = *(const f16x8*)&sX[swz512(row, k0)];
    *(f16x8*)(dst + c8 * 8) = v;
  }
}

// ---------------------------------------------------------------------------
// gemmT: 256x256 tile, K=512 (16 steps of 32), 1024 thr (16 waves of 64x64),
// double-buffered LDS staging via global_load_lds. D[i][j] = sum_k A[i,k]B[j,k].
// MODE 0: i = qkv col n in [0,1024) (Q,K), j = token  -> scatter to qkvP
// MODE 1: i = token, j = V col in [0,512)             -> scatter V^T to qkvP
// MODE 2: i = proj col n in [0,512), j = token        -> out fp32 + bias
// ---------------------------------------------------------------------------
template <int MODE>
__global__ __launch_bounds__(1024, 4) void gemmT(
    const _Float16* __restrict__ Afp, const _Float16* __restrict__ Bfp,
    _Float16* __restrict__ dst16, float* __restrict__ out,
    const float* __restrict__ bproj) {
  __shared__ __align__(16) _Float16 sG[2][2][16][512];
  const int tid = threadIdx.x;
  const int wid = tid >> 6;
  const int lane = tid & 63;
  const int lg = lane >> 4, lr = lane & 15;
  const int wr = wid >> 2, wc = wid & 3;
  const int r0 = blockIdx.x * 256, c0 = blockIdx.y * 256;

  const _Float16* aS = Afp + (size_t)((r0 >> 4) + wid) * 8192 + lane * 8;
  const _Float16* bS = Bfp + (size_t)((c0 >> 4) + wid) * 8192 + lane * 8;

  const f32x4 zero4 = {0.f, 0.f, 0.f, 0.f};
  f32x4 acc[4][4];
#pragma unroll
  for (int i = 0; i < 4; ++i)
#pragma unroll
    for (int j = 0; j < 4; ++j) acc[i][j] = zero4;

  stage16(aS, &sG[0][0][wid][0], lane);
  stage16(bS, &sG[0][1][wid][0], lane);
  __syncthreads();

  for (int kt = 0; kt < 16; ++kt) {
    const int cur = kt & 1;
    if (kt < 15) {
      stage16(aS + (kt + 1) * 512, &sG[cur ^ 1][0][wid][0], lane);
      stage16(bS + (kt + 1) * 512, &sG[cur ^ 1][1][wid][0], lane);
    }
    f16x8 af[4], bf[4];
#pragma unroll
    for (int mi = 0; mi < 4; ++mi)
      af[mi] = *(const f16x8*)&sG[cur][0][wr * 4 + mi][lane * 8];
#pragma unroll
    for (int ni = 0; ni < 4; ++ni)
      bf[ni] = *(const f16x8*)&sG[cur][1][wc * 4 + ni][lane * 8];
#pragma unroll
    for (int mi = 0; mi < 4; ++mi)
#pragma unroll
      for (int ni = 0; ni < 4; ++ni)
        acc[mi][ni] = MFMA16(af[mi], bf[ni], acc[mi][ni]);
    __syncthreads();
  }

  if constexpr (MODE == 0) {
    // lane holds qkv[token=tg][n=nb+rg], n<1024. Q/K FP-per-(w,h): rows=t,k=d.
#pragma unroll
    for (int mi = 0; mi < 4; ++mi) {
      int nb = r0 + wr * 64 + mi * 16 + lg * 4;
      int sec = nb >> 9, h = (nb >> 6) & 7, db = nb & 63;
      int e0 = db & 7;
      int coff = (db >> 5) * 512 + (((db >> 3) & 3) * 16) * 8 + e0;
#pragma unroll
      for (int ni = 0; ni < 4; ++ni) {
        int tg = c0 + wc * 64 + ni * 16 + lr;
        int w = tg >> 6, t = tg & 63;
        size_t pos = ((size_t)w * 24 + sec * 8 + h) * 4096 +
                     (size_t)((t >> 4) * 2) * 512 + coff + (t & 15) * 8;
        f16x4 hv;
        hv[0] = (_Float16)acc[mi][ni][0]; hv[1] = (_Float16)acc[mi][ni][1];
        hv[2] = (_Float16)acc[mi][ni][2]; hv[3] = (_Float16)acc[mi][ni][3];
        *(f16x4*)(dst16 + pos) = hv;
      }
    }
  } else if constexpr (MODE == 1) {
    // lane holds V[token=tb_glob+rg][cv]. V^T FP-per-(w,h): rows=d, k=t.
#pragma unroll
    for (int mi = 0; mi < 4; ++mi) {
      int tbg = r0 + wr * 64 + mi * 16 + lg * 4;
      int w = tbg >> 6, tb = tbg & 63;
      int e0 = tb & 7;
      int coff = (tb >> 5) * 512 + (((tb >> 3) & 3) * 16) * 8 + e0;
#pragma unroll
      for (int ni = 0; ni < 4; ++ni) {
        int cv = c0 + wc * 64 + ni * 16 + lr;  // [0,512)
        int h = cv >> 6, d = cv & 63;
        size_t pos = ((size_t)w * 24 + 16 + h) * 4096 +
                     (size_t)((d >> 4) * 2) * 512 + coff + (d & 15) * 8;
        f16x4 hv;
        hv[0] = (_Float16)acc[mi][ni][0]; hv[1] = (_Float16)acc[mi][ni][1];
        hv[2] = (_Float16)acc[mi][ni][2]; hv[3] = (_Float16)acc[mi][ni][3];
        *(f16x4*)(dst16 + pos) = hv;
      }
    }
  } else {
    // lane holds out[token=tg][n=nb+rg] pre-bias -> float4 row stores
#pragma unroll
    for (int mi = 0; mi < 4; ++mi) {
      int nb = r0 + wr * 64 + mi * 16 + lg * 4;
      float4 bi = *(const float4*)&bproj[nb];
#pragma unroll
      for (int ni = 0; ni < 4; ++ni) {
        int tg = c0 + wc * 64 + ni * 16 + lr;
        float4 v;
        v.x = acc[mi][ni][0] + bi.x; v.y = acc[mi][ni][1] + bi.y;
        v.z = acc[mi][ni][2] + bi.z; v.w = acc[mi][ni][3] + bi.w;
        *(float4*)&out[(size_t)tg * 512 + nb] = v;
      }
    }
  }
}

// ---------------------------------------------------------------------------
// attn_win: 1 block = 1 window, 512 thr. 2 rounds x 4 heads; wave=(head,part).
// QK^T from packed global frags; double softmax (R2-verified); PV as O^T
// (A=V^T frags, B=P via LDS); 8-B vector stores into hP (FP layout).
// ---------------------------------------------------------------------------
__global__ __launch_bounds__(512, 4) void attn_win(
    const _Float16* __restrict__ qkvP, _Float16* __restrict__ hP) {
  __shared__ __align__(16) _Float16 sP[4][4096];
  const int tid = threadIdx.x;
  const int wid = tid >> 6;
  const int lane = tid & 63;
  const int lg = lane >> 4, lr = lane & 15;
  const int hl = wid >> 1, part = wid & 1;
  const int w = blockIdx.x;
  const f32x4 zero4 = {0.f, 0.f, 0.f, 0.f};

  for (int hr = 0; hr < 2; ++hr) {
    const int h = hr * 4 + hl;
    const _Float16* Qb = qkvP + ((size_t)w * 24 + h) * 4096 + lane * 8;
    const _Float16* Kb = qkvP + ((size_t)w * 24 + 8 + h) * 4096 + lane * 8;
    const _Float16* Vb = qkvP + ((size_t)w * 24 + 16 + h) * 4096 + lane * 8;

    // ---- QK^T ----
    f16x8 afq[2][2], bfk[4][2];
#pragma unroll
    for (int rs = 0; rs < 2; ++rs)
#pragma unroll
      for (int dkt = 0; dkt < 2; ++dkt)
        afq[rs][dkt] = *(const f16x8*)(Qb + ((part * 2 + rs) * 2 + dkt) * 512);
#pragma unroll
    for (int nt = 0; nt < 4; ++nt)
#pragma unroll
      for (int dkt = 0; dkt < 2; ++dkt)
        bfk[nt][dkt] = *(const f16x8*)(Kb + (nt * 2 + dkt) * 512);
    f32x4 sacc[2][4];
#pragma unroll
    for (int rs = 0; rs < 2; ++rs)
#pragma unroll
      for (int nt = 0; nt < 4; ++nt) sacc[rs][nt] = zero4;
#pragma unroll
    for (int dkt = 0; dkt < 2; ++dkt)
#pragma unroll
      for (int rs = 0; rs < 2; ++rs)
#pragma unroll
        for (int nt = 0; nt < 4; ++nt)
          sacc[rs][nt] = MFMA16(afq[rs][dkt], bfk[nt][dkt], sacc[rs][nt]);

    // prefetch V (consumed after barrier; hides under softmax)
    f16x8 afv[2][2];
#pragma unroll
    for (int ds = 0; ds < 2; ++ds)
#pragma unroll
      for (int tkt = 0; tkt < 2; ++tkt)
        afv[ds][tkt] = *(const f16x8*)(Vb + ((part * 2 + ds) * 2 + tkt) * 512);

    // ---- double softmax (rows tq = rsg*16+lg*4+rg; cols nt*16+lr) ----
    float p2[2][4][4];
#pragma unroll
    for (int rs = 0; rs < 2; ++rs) {
      const int rsg = part * 2 + rs;
#pragma unroll
      for (int rg = 0; rg < 4; ++rg) {
        int row = rsg * 16 + lg * 4 + rg;
        float m = -1e30f;
#pragma unroll
        for (int nt = 0; nt < 4; ++nt) {
          int col = nt * 16 + lr;
          float v = (col <= row) ? sacc[rs][nt][rg] : -1e30f;
          m = fmaxf(m, v);
        }
#pragma unroll
        for (int off = 8; off >= 1; off >>= 1) m = fmaxf(m, __shfl_xor(m, off));
        float e[4], s1 = 0.f;
#pragma unroll
        for (int nt = 0; nt < 4; ++nt) {
          int col = nt * 16 + lr;
          e[nt] = (col <= row) ? __expf(sacc[rs][nt][rg] - m) : 0.f;
          s1 += e[nt];
        }
#pragma unroll
        for (int off = 8; off >= 1; off >>= 1) s1 += __shfl_xor(s1, off);
        float inv1 = 1.f / s1;
        float e2[4], s2 = 0.f;
#pragma unroll
        for (int nt = 0; nt < 4; ++nt) {
          e2[nt] = __expf(e[nt] * inv1);
          s2 += e2[nt];
        }
#pragma unroll
        for (int off = 8; off >= 1; off >>= 1) s2 += __shfl_xor(s2, off);
        float inv2 = 1.f / s2;
#pragma unroll
        for (int nt = 0; nt < 4; ++nt) p2[rs][nt][rg] = e2[nt] * inv2;
      }
    }

    // ---- P -> LDS in B-frag layout (rows=tq, k=tc) ----
#pragma unroll
    for (int rs = 0; rs < 2; ++rs) {
      const int rsg = part * 2 + rs;
#pragma unroll
      for (int nt = 0; nt < 4; ++nt) {
        int cbase = (rsg * 2 + (nt >> 1)) * 512 +
                    ((((nt * 2) + (lr >> 3)) & 3) * 16 + lg * 4) * 8 + (lr & 7);
#pragma unroll
        for (int rg = 0; rg < 4; ++rg)
          sP[hl][cbase + rg * 8] = (_Float16)p2[rs][nt][rg];
      }
    }
    __syncthreads();  // both parts' P ready

    // ---- O^T = V^T * P (A=afv rows=d, B=P rows=tq) ----
    f32x4 oacc[2][4];
#pragma unroll
    for (int ds = 0; ds < 2; ++ds)
#pragma unroll
      for (int ntq = 0; ntq < 4; ++ntq) oacc[ds][ntq] = zero4;
#pragma unroll
    for (int tkt = 0; tkt < 2; ++tkt) {
      f16x8 bfp[4];
#pragma unroll
      for (int ntq = 0; ntq < 4; ++ntq)
        bfp[ntq] = *(const f16x8*)&sP[hl][(ntq * 2 + tkt) * 512 + lane * 8];
#pragma unroll
      for (int ds = 0; ds < 2; ++ds)
#pragma unroll
        for (int ntq = 0; ntq < 4; ++ntq)
          oacc[ds][ntq] = MFMA16(afv[ds][tkt], bfp[ntq], oacc[ds][ntq]);
    }

    // ---- store O^T -> hP (FP rows=token, k=h*64+d); 8-B vector scatters ----
#pragma unroll
    for (int ds = 0; ds < 2; ++ds) {
      const int dsg = part * 2 + ds;
      const int e0 = (lg & 1) * 4;
      const int lgt = (dsg * 2 + (lg >> 1)) & 3;
#pragma unroll
      for (int ntq = 0; ntq < 4; ++ntq) {
        size_t pos = ((size_t)(w * 4 + ntq) * 16 + h * 2 + (dsg >> 1)) * 512 +
                     (lgt * 16 + lr) * 8 + e0;
        f16x4 hv;
        hv[0] = (_Float16)oacc[ds][ntq][0]; hv[1] = (_Float16)oacc[ds][ntq][1];
        hv[2] = (_Float16)oacc[ds][ntq][2]; hv[3] = (_Float16)oacc[ds][ntq][3];
        *(f16x4*)(hP + pos) = hv;
      }
    }
    __syncthreads();  // protect sP before next round
  }
}

// ---------------------------------------------------------------------------
// Fallback (verified R2 kernel) for small workspaces: fused, 128 KB LDS.
// ---------------------------------------------------------------------------
__global__ __launch_bounds__(512, 2) void attn_fused(
    const float* __restrict__ x, const _Float16* __restrict__ wqkvP,
    const _Float16* __restrict__ wprojP, const float* __restrict__ bproj,
    float* __restrict__ out) {
  __shared__ __align__(16) _Float16 sX[64 * 512];
  __shared__ __align__(16) _Float16 sHeads[4][2][4096];

  const int tid = threadIdx.x;
  const int wid = tid >> 6;
  const int lane = tid & 63;
  const int lg = lane >> 4;
  const int lr = lane & 15;

  _Float16* sQ0 = &sHeads[0][0][0];
  _Float16* sK0 = &sHeads[1][0][0];
  _Float16* sVT0 = &sHeads[2][0][0];
  _Float16* sPO0 = &sHeads[3][0][0];

  const float4* xv = (const float4*)(x + (size_t)blockIdx.x * 32768);
#pragma unroll
  for (int it = 0; it < 8; ++it) {
    int g = tid + it * 512;
    int r = g >> 6, c0 = (g & 63) << 3;
    float4 a = xv[(r << 7) + (c0 >> 2)];
    float4 b = xv[(r << 7) + (c0 >> 2) + 1];
    f16x8 hv;
    hv[0] = (_Float16)a.x; hv[1] = (_Float16)a.y;
    hv[2] = (_Float16)a.z; hv[3] = (_Float16)a.w;
    hv[4] = (_Float16)b.x; hv[5] = (_Float16)b.y;
    hv[6] = (_Float16)b.z; hv[7] = (_Float16)b.w;
    *(f16x8*)&sX[swz512(r, c0)] = hv;
  }
  const f32x4 zero4 = {0.f, 0.f, 0.f, 0.f};
  f32x4 accO[4][4];
#pragma unroll
  for (int i = 0; i < 4; ++i)
#pragma unroll
    for (int j = 0; j < 4; ++j) accO[i][j] = zero4;
  __syncthreads();

  for (int hp = 0; hp < 4; ++hp) {
    int hu[3], su[3], stu[3];
    const _Float16* bp[3];
    f32x4 acc[3][4];
#pragma unroll
    for (int i = 0; i < 3; ++i) {
      int u = wid + 8 * i;
      int hh = u & 1, v2 = u >> 1;
      int sec = v2 % 3, strip = v2 / 3;
      hu[i] = hh; su[i] = sec; stu[i] = strip;
      int r16 = sec * 32 + (hp * 2 + hh) * 4 + strip;
      bp[i] = wqkvP + (size_t)r16 * 8192 + lane * 8;
#pragma unroll
      for (int rt = 0; rt < 4; ++rt) acc[i][rt] = zero4;
    }
    f16x8 bf[3][3];
#pragma unroll
    for (int d = 0; d < 3; ++d)
#pragma unroll
      for (int i = 0; i < 3; ++i) bf[d][i] = *(const f16x8*)(bp[i] + d * 512);
    f16x8 af[2][4];
#pragma unroll
    for (int rt = 0; rt < 4; ++rt)
      af[0][rt] = *(const f16x8*)&sX[swz512(rt * 16 + lr, lg * 8)];
#pragma unroll
    for (int ks = 0; ks < 16; ++ks) {
      if (ks < 15) {
#pragma unroll
        for (int rt = 0; rt < 4; ++rt)
          af[(ks + 1) & 1][rt] =
              *(const f16x8*)&sX[swz512(rt * 16 + lr, (ks + 1) * 32 + lg * 8)];
      }
#pragma unroll
      for (int i = 0; i < 3; ++i)
#pragma unroll
        for (int rt = 0; rt < 4; ++rt)
          acc[i][rt] = MFMA16(af[ks & 1][rt], bf[ks % 3][i], acc[i][rt]);
      if (ks + 3 < 16) {
#pragma unroll
        for (int i = 0; i < 3; ++i)
          bf[ks % 3][i] = *(const f16x8*)(bp[i] + (ks + 3) * 512);
      }
    }
#pragma unroll
    for (int i = 0; i < 3; ++i) {
      int hh = hu[i], sec = su[i], strip = stu[i];
      _Float16* dq = sQ0 + hh * 4096;
      _Float16* dk = sK0 + hh * 4096;
      _Float16* dv = sVT0 + hh * 4096;
#pragma unroll
      for (int rt = 0; rt < 4; ++rt)
#pragma unroll
        for (int rg = 0; rg < 4; ++rg) {
          int row = rt * 16 + lg * 4 + rg;
          int col = strip * 16 + lr;
          _Float16 v = (_Float16)acc[i][rt][rg];
          if (sec == 0) dq[swz64(row, col)] = v;
          else if (sec == 1) dk[swz64(row, col)] = v;
          else dv[swz64(col, row)] = v;
        }
    }
    __syncthreads();
    {
      const int hh = wid >> 2;
      const int rs = wid & 3;
      const _Float16* mQ = sQ0 + hh * 4096;
      const _Float16* mK = sK0 + hh * 4096;
      const _Float16* mV = sVT0 + hh * 4096;
      _Float16* mP = sPO0 + hh * 4096;
      f32x4 sacc[4];
#pragma unroll
      for (int nt = 0; nt < 4; ++nt) sacc[nt] = zero4;
#pragma unroll
      for (int ks = 0; ks < 2; ++ks) {
        f16x8 afq = *(const f16x8*)&mQ[swz64(rs * 16 + lr, ks * 32 + lg * 8)];
#pragma unroll
        for (int nt = 0; nt < 4; ++nt) {
          f16x8 bfk = *(const f16x8*)&mK[swz64(nt * 16 + lr, ks * 32 + lg * 8)];
          sacc[nt] = MFMA16(afq, bfk, sacc[nt]);
        }
      }
      float p2[4][4];
#pragma unroll
      for (int rg = 0; rg < 4; ++rg) {
        int row = rs * 16 + lg * 4 + rg;
        float m = -1e30f;
#pragma unroll
        for (int nt = 0; nt < 4; ++nt) {
          int col = nt * 16 + lr;
          float v = (col <= row) ? sacc[nt][rg] : -1e30f;
          m = fmaxf(m, v);
        }
#pragma unroll
        for (int off = 8; off >= 1; off >>= 1) m = fmaxf(m, __shfl_xor(m, off));
        float e[4], s1 = 0.f;
#pragma unroll
        for (int nt = 0; nt < 4; ++nt) {
          int col = nt * 16 + lr;
          e[nt] = (col <= row) ? __expf(sacc[nt][rg] - m) : 0.f;
          s1 += e[nt];
        }
#pragma unroll
        for (int off = 8; off >= 1; off >>= 1) s1 += __shfl_xor(s1, off);
        float inv1 = 1.f / s1;
        float e2[4], s2 = 0.f;
#pragma unroll
        for (int nt = 0; nt < 4; ++nt) {
          e2[nt] = __expf(e[nt] * inv1);
          s2 += e2[nt];
        }
#pragma unroll
        for (int off = 8; off >= 1; off >>= 1) s2 += __shfl_xor(s2, off);
        float inv2 = 1.f / s2;
#pragma unroll
        for (int nt = 0; nt < 4; ++nt) p2[nt][rg] = e2[nt] * inv2;
      }
#pragma unroll
      for (int nt = 0; nt < 4; ++nt)
#pragma unroll
        for (int rg = 0; rg < 4; ++rg)
          mP[swz64(rs * 16 + lg * 4 + rg, nt * 16 + lr)] = (_Float16)p2[nt][rg];
      asm volatile("" ::: "memory");
      f32x4 oacc[4];
#pragma unroll
      for (int nt = 0; nt < 4; ++nt) oacc[nt] = zero4;
#pragma unroll
      for (int ks = 0; ks < 2; ++ks) {
        f16x8 afp = *(const f16x8*)&mP[swz64(rs * 16 + lr, ks * 32 + lg * 8)];
#pragma unroll
        for (int nt = 0; nt < 4; ++nt) {
          f16x8 bfv = *(const f16x8*)&mV[swz64(nt * 16 + lr, ks * 32 + lg * 8)];
          oacc[nt] = MFMA16(afp, bfv, oacc[nt]);
        }
      }
      asm volatile("" ::: "memory");
#pragma unroll
      for (int nt = 0; nt < 4; ++nt)
#pragma unroll
        for (int rg = 0; rg < 4; ++rg)
          mP[swz64(rs * 16 + lg * 4 + rg, nt * 16 + lr)] = (_Float16)oacc[nt][rg];
    }
    __syncthreads();
    {
      f16x8 bfC[2][4], afC[2][4];
#pragma unroll
      for (int rt = 0; rt < 4; ++rt)
        afC[0][rt] = *(const f16x8*)&sPO0[swz64(rt * 16 + lr, lg * 8)];
#pragma unroll
      for (int nt = 0; nt < 4; ++nt)
        bfC[0][nt] = *(const f16x8*)(wprojP + (size_t)(wid * 4 + nt) * 8192 +
                                     (size_t)(hp * 4) * 512 + lane * 8);
#pragma unroll
      for (int g = 0; g < 4; ++g) {
        if (g < 3) {
          int hn = (g + 1) >> 1, kn = (g + 1) & 1;
#pragma unroll
          for (int rt = 0; rt < 4; ++rt)
            afC[(g + 1) & 1][rt] = *(const f16x8*)&sPO0[hn * 4096 +
                swz64(rt * 16 + lr, kn * 32 + lg * 8)];
#pragma unroll
          for (int nt = 0; nt < 4; ++nt)
            bfC[(g + 1) & 1][nt] =
                *(const f16x8*)(wprojP + (size_t)(wid * 4 + nt) * 8192 +
                                (size_t)(hp * 4 + g + 1) * 512 + lane * 8);
        }
#pragma unroll
        for (int nt = 0; nt < 4; ++nt)
#pragma unroll
          for (int rt = 0; rt < 4; ++rt)
            accO[rt][nt] = MFMA16(afC[g & 1][rt], bfC[g & 1][nt], accO[rt][nt]);
      }
    }
  }
  __syncthreads();
  float bias_r[4];
#pragma unroll
  for (int nt = 0; nt < 4; ++nt) bias_r[nt] = bproj[wid * 64 + nt * 16 + lr];
  float* sEp = (float*)&sHeads[0][0][0];
  size_t base = (size_t)blockIdx.x * 32768;
#pragma unroll
  for (int half = 0; half < 2; ++half) {
#pragma unroll
    for (int rr = 0; rr < 2; ++rr) {
      int rt = half * 2 + rr;
#pragma unroll
      for (int nt = 0; nt < 4; ++nt)
#pragma unroll
        for (int rg = 0; rg < 4; ++rg) {
          int r = rr * 16 + lg * 4 + rg;
          int c = wid * 64 + nt * 16 + lr;
          sEp[r * 512 + (c ^ (((r >> 2) & 1) << 4))] = accO[rt][nt][rg] + bias_r[nt];
        }
    }
    __syncthreads();
#pragma unroll
    for (int j = 0; j < 8; ++j) {
      int f4 = tid + j * 512;
      int r = f4 >> 7;
      int c0 = (f4 & 127) << 2;
      float4 v = *(const float4*)&sEp[r * 512 + (c0 ^ (((r >> 2) & 1) << 4))];
      *(float4*)&out[base + (size_t)(half * 32 + r) * 512 + c0] = v;
    }
    if (half == 0) __syncthreads();
  }
}

extern "C" void kernel_launch(void* const* d_in, const int* in_sizes, int n_in,
                              void* d_out, int out_size, void* d_ws, size_t ws_size,
                              hipStream_t stream) {
  const float* x = (const float*)d_in[0];
  const float* Wqkv = (const float*)d_in[1];
  const float* Wproj = (const float*)d_in[2];
  const float* bproj = (const float*)d_in[3];
  float* out = (float*)d_out;

  const size_t W1 = 786432, W2 = 262144, XN = 33554432;
  const size_t QN = 100663296, HN = 33554432;
  _Float16* wqkvP = (_Float16*)d_ws;
  _Float16* wprojP = wqkvP + W1;
  _Float16* xP = wprojP + W2;
  _Float16* qkvP = xP + XN;
  _Float16* hP = qkvP + QN;
  const size_t NEED = (W1 + W2 + XN + QN + HN) * 2;

  prep_weights<<<dim3(4096), dim3(256), 0, stream>>>(Wqkv, Wproj, wqkvP, wprojP);
  if (ws_size >= NEED) {
    prep_x<<<dim3(1024), dim3(512), 0, stream>>>(x, xP);
    // Q,K cols (transposed): A rows = n' in [0,1024), B rows = tokens
    gemmT<0><<<dim3(4, 256), dim3(1024), 0, stream>>>(wqkvP, xP, qkvP, nullptr, nullptr);
    // V cols (normal): A rows = tokens, B rows = V weight rows (offset 1024)
    gemmT<1><<<dim3(256, 2), dim3(1024), 0, stream>>>(xP, wqkvP + (size_t)64 * 8192,
                                                      qkvP, nullptr, nullptr);
    attn_win<<<dim3(1024), dim3(512), 0, stream>>>(qkvP, hP);
    // proj (transposed): A rows = n in [0,512), B rows = tokens
    gemmT<2><<<dim3(2, 256), dim3(1024), 0, stream>>>(wprojP, hP, nullptr, out, bproj);
  } else {
    attn_fused<<<dim3(1024), dim3(512), 0, stream>>>(x, wqkvP, wprojP, bproj, out);
  }
}

// Round 6
// 295.463 us; speedup vs baseline: 3.5297x; 1.0585x over previous
//
#include <hip/hip_runtime.h>

// x[16,4096,512] fp32 -> windows [1024, 64, 512]
//   qkv = xw @ Wqkv[512,1536]; per head (8 x 64d): S = QK^T/8, causal mask,
//   softmax, softmax AGAIN (no re-mask), out = P2 @ V; concat; @ Wproj + bproj.
//
// Pipeline: prep_weights, prep_x (pack fp16 fragments) ->
//   gemm8<0>: Q/K cols (transposed orientation)        -> qkvP packed
//   gemm8<1>: V cols (normal orientation)              -> qkvP packed (V^T)
//   attn_win: per-window double-softmax attention      -> hP packed
//   gemm8<2>: out^T = Wproj^T @ hOut^T + bias          -> out fp32
//
// FP(R) packing of M[r][k], k in [0,512):
//   pos(r,k) = ((r>>4)*16 + (k>>5))*512 + (((k>>3)&3)*16 + (r&15))*8 + (k&7)
// gemm8 = 8-phase counted-vmcnt schedule (T3+T4+T5), 256x256 tile, BK=64.

typedef _Float16 f16x8 __attribute__((ext_vector_type(8)));
typedef _Float16 f16x4 __attribute__((ext_vector_type(4)));
typedef float f32x4 __attribute__((ext_vector_type(4)));

#define MFMA16(a, b, c) __builtin_amdgcn_mfma_f32_16x16x32_f16((a), (b), (c), 0, 0, 0)

__device__ __forceinline__ int swz64(int r, int c) { return r * 64 + (c ^ ((r & 7) << 3)); }
__device__ __forceinline__ int swz512(int r, int c) { return r * 512 + (c ^ ((r & 7) << 3)); }

typedef const __attribute__((address_space(1))) void* gas1_t;
typedef __attribute__((address_space(3))) void* las3_t;

// async global->LDS: 64 lanes x 16B -> 1KB chunk at wave-uniform lbase
__device__ __forceinline__ void stage16(const _Float16* g, _Float16* lbase, int lane) {
#if __has_builtin(__builtin_amdgcn_global_load_lds)
  __builtin_amdgcn_global_load_lds((gas1_t)(const void*)g, (las3_t)(void*)lbase, 16, 0, 0);
#else
  *(f16x8*)(lbase + lane * 8) = *(const f16x8*)g;
#endif
}

#define CFENCE() asm volatile("" ::: "memory")
#define BARRIER() do { CFENCE(); __builtin_amdgcn_s_barrier(); CFENCE(); } while (0)

// ---------------------------------------------------------------------------
// prep_weights: wqkvP = FP(Wqkv^T) rows 0..1535 (Q rows scaled 0.125);
//               wprojP = FP(Wproj^T) rows 0..511.
// ---------------------------------------------------------------------------
__global__ void prep_weights(const float* __restrict__ Wqkv,
                             const float* __restrict__ Wproj,
                             _Float16* __restrict__ wqkvP,
                             _Float16* __restrict__ wprojP) {
  int idx = blockIdx.x * blockDim.x + threadIdx.x;
  if (idx < 786432) {
    int r16 = idx >> 13;
    int rem = idx & 8191;
    int kt = rem >> 9;
    int lane = (rem >> 3) & 63;
    int e = rem & 7;
    int row = r16 * 16 + (lane & 15);
    int k = kt * 32 + (lane >> 4) * 8 + e;
    float v = Wqkv[k * 1536 + row];
    if (row < 512) v *= 0.125f;
    wqkvP[idx] = (_Float16)v;
  } else {
    int j = idx - 786432;
    int r16 = j >> 13;
    int rem = j & 8191;
    int kt = rem >> 9;
    int lane = (rem >> 3) & 63;
    int e = rem & 7;
    int n = r16 * 16 + (lane & 15);
    int k = kt * 32 + (lane >> 4) * 8 + e;
    wprojP[j] = (_Float16)Wproj[k * 512 + n];
  }
}

// ---------------------------------------------------------------------------
// prep_x: xP = FP(x fp16, 65536 rows)
// ---------------------------------------------------------------------------
__global__ __launch_bounds__(512) void prep_x(const float* __restrict__ x,
                                              _Float16* __restrict__ xP) {
  __shared__ __align__(16) _Float16 sX[64 * 512];
  const int tid = threadIdx.x;
  const float4* xv = (const float4*)(x + (size_t)blockIdx.x * 32768);
#pragma unroll
  for (int it = 0; it < 8; ++it) {
    int g = tid + it * 512;
    int r = g >> 6, c0 = (g & 63) << 3;
    float4 a = xv[(r << 7) + (c0 >> 2)];
    float4 b = xv[(r << 7) + (c0 >> 2) + 1];
    f16x8 hv;
    hv[0] = (_Float16)a.x; hv[1] = (_Float16)a.y;
    hv[2] = (_Float16)a.z; hv[3] = (_Float16)a.w;
    hv[4] = (_Float16)b.x; hv[5] = (_Float16)b.y;
    hv[6] = (_Float16)b.z; hv[7] = (_Float16)b.w;
    *(f16x8*)&sX[swz512(r, c0)] = hv;
  }
  __syncthreads();
  _Float16* dst = xP + (size_t)blockIdx.x * 32768;
#pragma unroll
  for (int it = 0; it < 8; ++it) {
    int c8 = tid + it * 512;
    int rt = c8 >> 10, ks = (c8 >> 6) & 15, ln = c8 & 63;
    int row = rt * 16 + (ln & 15);
    int k0 = ks * 32 + (ln >> 4) * 8;
    f16x8 v = *(const f16x8*)&sX[swz512(row, k0)];
    *(f16x8*)(dst + c8 * 8) = v;
  }
}

// ---------------------------------------------------------------------------
// gemm8 helpers: register fragment loads from packed LDS (conflict-free linear)
// ---------------------------------------------------------------------------
__device__ __forceinline__ void ds_a4(const _Float16* base, int chunkBase, int lane8,
                                      f16x8 (&a)[4][2]) {
#pragma unroll
  for (int mi = 0; mi < 4; ++mi)
#pragma unroll
    for (int kt = 0; kt < 2; ++kt)
      a[mi][kt] = *(const f16x8*)(base + (chunkBase + mi * 2 + kt) * 512 + lane8);
}

__device__ __forceinline__ void ds_b2(const _Float16* base, int chunkBase, int lane8,
                                      f16x8 (&b)[2][2]) {
#pragma unroll
  for (int ni = 0; ni < 2; ++ni)
#pragma unroll
    for (int kt = 0; kt < 2; ++kt)
      b[ni][kt] = *(const f16x8*)(base + (chunkBase + ni * 2 + kt) * 512 + lane8);
}

__device__ __forceinline__ void mma_q(const f16x8 (&a)[4][2], const f16x8 (&b)[2][2],
                                      f32x4 (&acc)[8][4], int rh, int ch) {
  __builtin_amdgcn_s_setprio(1);
#pragma unroll
  for (int kt = 0; kt < 2; ++kt)
#pragma unroll
    for (int mi = 0; mi < 4; ++mi)
#pragma unroll
      for (int ni = 0; ni < 2; ++ni)
        acc[rh * 4 + mi][ch * 2 + ni] =
            MFMA16(a[mi][kt], b[ni][kt], acc[rh * 4 + mi][ch * 2 + ni]);
  __builtin_amdgcn_s_setprio(0);
}

// ---------------------------------------------------------------------------
// gemm8: D[i][j] = sum_k A[i,k] B[j,k], M=rTiles*256 (A rows), N (B rows).
// 8 waves (512 thr); wave owns 128x64; LDS 128KB (2 slots x A/B x 32 chunks).
// 8-phase schedule, vmcnt(2) at phases 0/4 only, setprio around MFMA.
// MODE 0: A=Wqkv^T Q/K rows, B=tokens -> scatter Q/K to qkvP
// MODE 1: A=tokens, B=V weight rows  -> scatter V^T to qkvP
// MODE 2: A=Wproj^T rows, B=tokens   -> out fp32 + bias
// ---------------------------------------------------------------------------
template <int MODE>
__global__ __launch_bounds__(512, 2) void gemm8(
    const _Float16* __restrict__ Afp, const _Float16* __restrict__ Bfp,
    _Float16* __restrict__ dst16, float* __restrict__ out,
    const float* __restrict__ bproj, int rTiles) {
  __shared__ __align__(16) _Float16 sG[2][2][32][512];  // [slot][A/B][chunk][1KB]
  const int tid = threadIdx.x;
  const int wid = tid >> 6;
  const int lane = tid & 63;
  const int lg = lane >> 4, lr = lane & 15;
  const int wr = wid >> 2, wc = wid & 3;
  const int wr8 = wr * 8, wc4 = wc * 4, lane8 = lane * 8;

  // XCD-chunked bijective swizzle (nwg % 8 == 0 for all modes)
  const int nwg = gridDim.x;
  const int bid = blockIdx.x;
  const int swz = (bid & 7) * (nwg >> 3) + (bid >> 3);
  const int r0 = (swz % rTiles) * 256, c0 = (swz / rTiles) * 256;

  const _Float16* Abase = Afp + (size_t)(r0 >> 4) * 8192 + lane8;
  const _Float16* Bbase = Bfp + (size_t)(c0 >> 4) * 8192 + lane8;
  const _Float16* sA0 = &sG[0][0][0][0];
  const _Float16* sB0 = &sG[0][1][0][0];
  const _Float16* sA1 = &sG[1][0][0][0];
  const _Float16* sB1 = &sG[1][1][0][0];

  // stage half-tile h (0:A lo,1:A hi,2:B lo,3:B hi) of K-tile T into slot s
  auto STAGE = [&](int s, int h, int T) {
    const int r16 = ((h & 1) << 3) + wid;
    if (h < 2) {
      const _Float16* src = Abase + (size_t)r16 * 8192 + (size_t)T * 1024;
      stage16(src, &sG[s][0][r16 * 2][0], lane);
      stage16(src + 512, &sG[s][0][r16 * 2 + 1][0], lane);
    } else {
      const _Float16* src = Bbase + (size_t)r16 * 8192 + (size_t)T * 1024;
      stage16(src, &sG[s][1][r16 * 2][0], lane);
      stage16(src + 512, &sG[s][1][r16 * 2 + 1][0], lane);
    }
  };

  const f32x4 zero4 = {0.f, 0.f, 0.f, 0.f};
  f32x4 acc[8][4];
#pragma unroll
  for (int i = 0; i < 8; ++i)
#pragma unroll
    for (int j = 0; j < 4; ++j) acc[i][j] = zero4;

  f16x8 a[4][2], b0[2][2], b1[2][2];

  // prologue: tile 0 -> slot 0 (8 loads/wave)
#pragma unroll
  for (int h = 0; h < 4; ++h) STAGE(0, h, 0);

  for (int i = 0; i < 4; ++i) {
    const int T1 = 2 * i + 1;
    const int T2 = (2 * i + 2 > 7) ? 7 : 2 * i + 2;  // clamp: harmless re-stage
    // ======== phases 0-3: compute slot0 (tile 2i), stage T1 -> slot1 ========
    // p0: quadrant (0,0)
    STAGE(1, 0, T1);
    asm volatile("s_waitcnt vmcnt(2)" ::: "memory");
    BARRIER();
    ds_a4(sA0, wr8 * 2, lane8, a);
    ds_b2(sB0, wc4 * 2, lane8, b0);
    mma_q(a, b0, acc, 0, 0);
    BARRIER();
    // p1: quadrant (0,1)
    ds_b2(sB0, (wc4 + 2) * 2, lane8, b1);
    STAGE(1, 1, T1);
    BARRIER();
    mma_q(a, b1, acc, 0, 1);
    BARRIER();
    // p2: quadrant (1,1)
    ds_a4(sA0, (wr8 + 4) * 2, lane8, a);
    STAGE(1, 2, T1);
    BARRIER();
    mma_q(a, b1, acc, 1, 1);
    BARRIER();
    // p3: quadrant (1,0)
    STAGE(1, 3, T1);
    BARRIER();
    mma_q(a, b0, acc, 1, 0);
    BARRIER();
    // ======== phases 4-7: compute slot1 (tile 2i+1), stage T2 -> slot0 ======
    // p4
    STAGE(0, 0, T2);
    asm volatile("s_waitcnt vmcnt(2)" ::: "memory");
    BARRIER();
    ds_a4(sA1, wr8 * 2, lane8, a);
    ds_b2(sB1, wc4 * 2, lane8, b0);
    mma_q(a, b0, acc, 0, 0);
    BARRIER();
    // p5
    ds_b2(sB1, (wc4 + 2) * 2, lane8, b1);
    STAGE(0, 1, T2);
    BARRIER();
    mma_q(a, b1, acc, 0, 1);
    BARRIER();
    // p6
    ds_a4(sA1, (wr8 + 4) * 2, lane8, a);
    STAGE(0, 2, T2);
    BARRIER();
    mma_q(a, b1, acc, 1, 1);
    BARRIER();
    // p7
    STAGE(0, 3, T2);
    BARRIER();
    mma_q(a, b0, acc, 1, 0);
    BARRIER();
  }

  // ============================ epilogue =================================
  if constexpr (MODE == 0) {
#pragma unroll
    for (int mi = 0; mi < 8; ++mi) {
      int nb = r0 + wr * 128 + mi * 16 + lg * 4;
      int sec = nb >> 9, h = (nb >> 6) & 7, db = nb & 63;
      int coff = (db >> 5) * 512 + (((db >> 3) & 3) * 16) * 8 + (db & 7);
#pragma unroll
      for (int ni = 0; ni < 4; ++ni) {
        int tg = c0 + wc * 64 + ni * 16 + lr;
        int w = tg >> 6, t = tg & 63;
        size_t pos = ((size_t)w * 24 + sec * 8 + h) * 4096 +
                     (size_t)((t >> 4) * 2) * 512 + coff + (t & 15) * 8;
        f16x4 hv;
        hv[0] = (_Float16)acc[mi][ni][0]; hv[1] = (_Float16)acc[mi][ni][1];
        hv[2] = (_Float16)acc[mi][ni][2]; hv[3] = (_Float16)acc[mi][ni][3];
        *(f16x4*)(dst16 + pos) = hv;
      }
    }
  } else if constexpr (MODE == 1) {
#pragma unroll
    for (int mi = 0; mi < 8; ++mi) {
      int tbg = r0 + wr * 128 + mi * 16 + lg * 4;
      int w = tbg >> 6, tb = tbg & 63;
      int coff = (tb >> 5) * 512 + (((tb >> 3) & 3) * 16) * 8 + (tb & 7);
#pragma unroll
      for (int ni = 0; ni < 4; ++ni) {
        int cv = c0 + wc * 64 + ni * 16 + lr;
        int h = cv >> 6, d = cv & 63;
        size_t pos = ((size_t)w * 24 + 16 + h) * 4096 +
                     (size_t)((d >> 4) * 2) * 512 + coff + (d & 15) * 8;
        f16x4 hv;
        hv[0] = (_Float16)acc[mi][ni][0]; hv[1] = (_Float16)acc[mi][ni][1];
        hv[2] = (_Float16)acc[mi][ni][2]; hv[3] = (_Float16)acc[mi][ni][3];
        *(f16x4*)(dst16 + pos) = hv;
      }
    }
  } else {
#pragma unroll
    for (int mi = 0; mi < 8; ++mi) {
      int nb = r0 + wr * 128 + mi * 16 + lg * 4;
      float4 bi = *(const float4*)&bproj[nb];
#pragma unroll
      for (int ni = 0; ni < 4; ++ni) {
        int tg = c0 + wc * 64 + ni * 16 + lr;
        float4 v;
        v.x = acc[mi][ni][0] + bi.x; v.y = acc[mi][ni][1] + bi.y;
        v.z = acc[mi][ni][2] + bi.z; v.w = acc[mi][ni][3] + bi.w;
        *(float4*)&out[(size_t)tg * 512 + nb] = v;
      }
    }
  }
}

// ---------------------------------------------------------------------------
// attn_win: 1 block = 1 window, 512 thr. 2 rounds x 4 heads; wave=(head,part).
// (verified R5)
// ---------------------------------------------------------------------------
__global__ __launch_bounds__(512, 4) void attn_win(
    const _Float16* __restrict__ qkvP, _Float16* __restrict__ hP) {
  __shared__ __align__(16) _Float16 sP[4][4096];
  const int tid = threadIdx.x;
  const int wid = tid >> 6;
  const int lane = tid & 63;
  const int lg = lane >> 4, lr = lane & 15;
  const int hl = wid >> 1, part = wid & 1;
  const int w = blockIdx.x;
  const f32x4 zero4 = {0.f, 0.f, 0.f, 0.f};

  for (int hr = 0; hr < 2; ++hr) {
    const int h = hr * 4 + hl;
    const _Float16* Qb = qkvP + ((size_t)w * 24 + h) * 4096 + lane * 8;
    const _Float16* Kb = qkvP + ((size_t)w * 24 + 8 + h) * 4096 + lane * 8;
    const _Float16* Vb = qkvP + ((size_t)w * 24 + 16 + h) * 4096 + lane * 8;

    f16x8 afq[2][2], bfk[4][2];
#pragma unroll
    for (int rs = 0; rs < 2; ++rs)
#pragma unroll
      for (int dkt = 0; dkt < 2; ++dkt)
        afq[rs][dkt] = *(const f16x8*)(Qb + ((part * 2 + rs) * 2 + dkt) * 512);
#pragma unroll
    for (int nt = 0; nt < 4; ++nt)
#pragma unroll
      for (int dkt = 0; dkt < 2; ++dkt)
        bfk[nt][dkt] = *(const f16x8*)(Kb + (nt * 2 + dkt) * 512);
    f32x4 sacc[2][4];
#pragma unroll
    for (int rs = 0; rs < 2; ++rs)
#pragma unroll
      for (int nt = 0; nt < 4; ++nt) sacc[rs][nt] = zero4;
#pragma unroll
    for (int dkt = 0; dkt < 2; ++dkt)
#pragma unroll
      for (int rs = 0; rs < 2; ++rs)
#pragma unroll
        for (int nt = 0; nt < 4; ++nt)
          sacc[rs][nt] = MFMA16(afq[rs][dkt], bfk[nt][dkt], sacc[rs][nt]);

    f16x8 afv[2][2];
#pragma unroll
    for (int ds = 0; ds < 2; ++ds)
#pragma unroll
      for (int tkt = 0; tkt < 2; ++tkt)
        afv[ds][tkt] = *(const f16x8*)(Vb + ((part * 2 + ds) * 2 + tkt) * 512);

    float p2[2][4][4];
#pragma unroll
    for (int rs = 0; rs < 2; ++rs) {
      const int rsg = part * 2 + rs;
#pragma unroll
      for (int rg = 0; rg < 4; ++rg) {
        int row = rsg * 16 + lg * 4 + rg;
        float m = -1e30f;
#pragma unroll
        for (int nt = 0; nt < 4; ++nt) {
          int col = nt * 16 + lr;
          float v = (col <= row) ? sacc[rs][nt][rg] : -1e30f;
          m = fmaxf(m, v);
        }
#pragma unroll
        for (int off = 8; off >= 1; off >>= 1) m = fmaxf(m, __shfl_xor(m, off));
        float e[4], s1 = 0.f;
#pragma unroll
        for (int nt = 0; nt < 4; ++nt) {
          int col = nt * 16 + lr;
          e[nt] = (col <= row) ? __expf(sacc[rs][nt][rg] - m) : 0.f;
          s1 += e[nt];
        }
#pragma unroll
        for (int off = 8; off >= 1; off >>= 1) s1 += __shfl_xor(s1, off);
        float inv1 = 1.f / s1;
        float e2[4], s2 = 0.f;
#pragma unroll
        for (int nt = 0; nt < 4; ++nt) {
          e2[nt] = __expf(e[nt] * inv1);
          s2 += e2[nt];
        }
#pragma unroll
        for (int off = 8; off >= 1; off >>= 1) s2 += __shfl_xor(s2, off);
        float inv2 = 1.f / s2;
#pragma unroll
        for (int nt = 0; nt < 4; ++nt) p2[rs][nt][rg] = e2[nt] * inv2;
      }
    }

#pragma unroll
    for (int rs = 0; rs < 2; ++rs) {
      const int rsg = part * 2 + rs;
#pragma unroll
      for (int nt = 0; nt < 4; ++nt) {
        int cbase = (rsg * 2 + (nt >> 1)) * 512 +
                    ((((nt * 2) + (lr >> 3)) & 3) * 16 + lg * 4) * 8 + (lr & 7);
#pragma unroll
        for (int rg = 0; rg < 4; ++rg)
          sP[hl][cbase + rg * 8] = (_Float16)p2[rs][nt][rg];
      }
    }
    __syncthreads();

    f32x4 oacc[2][4];
#pragma unroll
    for (int ds = 0; ds < 2; ++ds)
#pragma unroll
      for (int ntq = 0; ntq < 4; ++ntq) oacc[ds][ntq] = zero4;
#pragma unroll
    for (int tkt = 0; tkt < 2; ++tkt) {
      f16x8 bfp[4];
#pragma unroll
      for (int ntq = 0; ntq < 4; ++ntq)
        bfp[ntq] = *(const f16x8*)&sP[hl][(ntq * 2 + tkt) * 512 + lane * 8];
#pragma unroll
      for (int ds = 0; ds < 2; ++ds)
#pragma unroll
        for (int ntq = 0; ntq < 4; ++ntq)
          oacc[ds][ntq] = MFMA16(afv[ds][tkt], bfp[ntq], oacc[ds][ntq]);
    }

#pragma unroll
    for (int ds = 0; ds < 2; ++ds) {
      const int dsg = part * 2 + ds;
      const int e0 = (lg & 1) * 4;
      const int lgt = (dsg * 2 + (lg >> 1)) & 3;
#pragma unroll
      for (int ntq = 0; ntq < 4; ++ntq) {
        size_t pos = ((size_t)(w * 4 + ntq) * 16 + h * 2 + (dsg >> 1)) * 512 +
                     (lgt * 16 + lr) * 8 + e0;
        f16x4 hv;
        hv[0] = (_Float16)oacc[ds][ntq][0]; hv[1] = (_Float16)oacc[ds][ntq][1];
        hv[2] = (_Float16)oacc[ds][ntq][2]; hv[3] = (_Float16)oacc[ds][ntq][3];
        *(f16x4*)(hP + pos) = hv;
      }
    }
    __syncthreads();
  }
}

// ---------------------------------------------------------------------------
// Fallback (verified R2 kernel) for small workspaces: fused, 128 KB LDS.
// ---------------------------------------------------------------------------
__global__ __launch_bounds__(512, 2) void attn_fused(
    const float* __restrict__ x, const _Float16* __restrict__ wqkvP,
    const _Float16* __restrict__ wprojP, const float* __restrict__ bproj,
    float* __restrict__ out) {
  __shared__ __align__(16) _Float16 sX[64 * 512];
  __shared__ __align__(16) _Float16 sHeads[4][2][4096];

  const int tid = threadIdx.x;
  const int wid = tid >> 6;
  const int lane = tid & 63;
  const int lg = lane >> 4;
  const int lr = lane & 15;

  _Float16* sQ0 = &sHeads[0][0][0];
  _Float16* sK0 = &sHeads[1][0][0];
  _Float16* sVT0 = &sHeads[2][0][0];
  _Float16* sPO0 = &sHeads[3][0][0];

  const float4* xv = (const float4*)(x + (size_t)blockIdx.x * 32768);
#pragma unroll
  for (int it = 0; it < 8; ++it) {
    int g = tid + it * 512;
    int r = g >> 6, c0 = (g & 63) << 3;
    float4 a = xv[(r << 7) + (c0 >> 2)];
    float4 b = xv[(r << 7) + (c0 >> 2) + 1];
    f16x8 hv;
    hv[0] = (_Float16)a.x; hv[1] = (_Float16)a.y;
    hv[2] = (_Float16)a.z; hv[3] = (_Float16)a.w;
    hv[4] = (_Float16)b.x; hv[5] = (_Float16)b.y;
    hv[6] = (_Float16)b.z; hv[7] = (_Float16)b.w;
    *(f16x8*)&sX[swz512(r, c0)] = hv;
  }
  const f32x4 zero4 = {0.f, 0.f, 0.f, 0.f};
  f32x4 accO[4][4];
#pragma unroll
  for (int i = 0; i < 4; ++i)
#pragma unroll
    for (int j = 0; j < 4; ++j) accO[i][j] = zero4;
  __syncthreads();

  for (int hp = 0; hp < 4; ++hp) {
    int hu[3], su[3], stu[3];
    const _Float16* bp[3];
    f32x4 acc[3][4];
#pragma unroll
    for (int i = 0; i < 3; ++i) {
      int u = wid + 8 * i;
      int hh = u & 1, v2 = u >> 1;
      int sec = v2 % 3, strip = v2 / 3;
      hu[i] = hh; su[i] = sec; stu[i] = strip;
      int r16 = sec * 32 + (hp * 2 + hh) * 4 + strip;
      bp[i] = wqkvP + (size_t)r16 * 8192 + lane * 8;
#pragma unroll
      for (int rt = 0; rt < 4; ++rt) acc[i][rt] = zero4;
    }
    f16x8 bf[3][3];
#pragma unroll
    for (int d = 0; d < 3; ++d)
#pragma unroll
      for (int i = 0; i < 3; ++i) bf[d][i] = *(const f16x8*)(bp[i] + d * 512);
    f16x8 af[2][4];
#pragma unroll
    for (int rt = 0; rt < 4; ++rt)
      af[0][rt] = *(const f16x8*)&sX[swz512(rt * 16 + lr, lg * 8)];
#pragma unroll
    for (int ks = 0; ks < 16; ++ks) {
      if (ks < 15) {
#pragma unroll
        for (int rt = 0; rt < 4; ++rt)
          af[(ks + 1) & 1][rt] =
              *(const f16x8*)&sX[swz512(rt * 16 + lr, (ks + 1) * 32 + lg * 8)];
      }
#pragma unroll
      for (int i = 0; i < 3; ++i)
#pragma unroll
        for (int rt = 0; rt < 4; ++rt)
          acc[i][rt] = MFMA16(af[ks & 1][rt], bf[ks % 3][i], acc[i][rt]);
      if (ks + 3 < 16) {
#pragma unroll
        for (int i = 0; i < 3; ++i)
          bf[ks % 3][i] = *(const f16x8*)(bp[i] + (ks + 3) * 512);
      }
    }
#pragma unroll
    for (int i = 0; i < 3; ++i) {
      int hh = hu[i], sec = su[i], strip = stu[i];
      _Float16* dq = sQ0 + hh * 4096;
      _Float16* dk = sK0 + hh * 4096;
      _Float16* dv = sVT0 + hh * 4096;
#pragma unroll
      for (int rt = 0; rt < 4; ++rt)
#pragma unroll
        for (int rg = 0; rg < 4; ++rg) {
          int row = rt * 16 + lg * 4 + rg;
          int col = strip * 16 + lr;
          _Float16 v = (_Float16)acc[i][rt][rg];
          if (sec == 0) dq[swz64(row, col)] = v;
          else if (sec == 1) dk[swz64(row, col)] = v;
          else dv[swz64(col, row)] = v;
        }
    }
    __syncthreads();
    {
      const int hh = wid >> 2;
      const int rs = wid & 3;
      const _Float16* mQ = sQ0 + hh * 4096;
      const _Float16* mK = sK0 + hh * 4096;
      const _Float16* mV = sVT0 + hh * 4096;
      _Float16* mP = sPO0 + hh * 4096;
      f32x4 sacc[4];
#pragma unroll
      for (int nt = 0; nt < 4; ++nt) sacc[nt] = zero4;
#pragma unroll
      for (int ks = 0; ks < 2; ++ks) {
        f16x8 afq = *(const f16x8*)&mQ[swz64(rs * 16 + lr, ks * 32 + lg * 8)];
#pragma unroll
        for (int nt = 0; nt < 4; ++nt) {
          f16x8 bfk = *(const f16x8*)&mK[swz64(nt * 16 + lr, ks * 32 + lg * 8)];
          sacc[nt] = MFMA16(afq, bfk, sacc[nt]);
        }
      }
      float p2[4][4];
#pragma unroll
      for (int rg = 0; rg < 4; ++rg) {
        int row = rs * 16 + lg * 4 + rg;
        float m = -1e30f;
#pragma unroll
        for (int nt = 0; nt < 4; ++nt) {
          int col = nt * 16 + lr;
          float v = (col <= row) ? sacc[nt][rg] : -1e30f;
          m = fmaxf(m, v);
        }
#pragma unroll
        for (int off = 8; off >= 1; off >>= 1) m = fmaxf(m, __shfl_xor(m, off));
        float e[4], s1 = 0.f;
#pragma unroll
        for (int nt = 0; nt < 4; ++nt) {
          int col = nt * 16 + lr;
          e[nt] = (col <= row) ? __expf(sacc[nt][rg] - m) : 0.f;
          s1 += e[nt];
        }
#pragma unroll
        for (int off = 8; off >= 1; off >>= 1) s1 += __shfl_xor(s1, off);
        float inv1 = 1.f / s1;
        float e2[4], s2 = 0.f;
#pragma unroll
        for (int nt = 0; nt < 4; ++nt) {
          e2[nt] = __expf(e[nt] * inv1);
          s2 += e2[nt];
        }
#pragma unroll
        for (int off = 8; off >= 1; off >>= 1) s2 += __shfl_xor(s2, off);
        float inv2 = 1.f / s2;
#pragma unroll
        for (int nt = 0; nt < 4; ++nt) p2[nt][rg] = e2[nt] * inv2;
      }
#pragma unroll
      for (int nt = 0; nt < 4; ++nt)
#pragma unroll
        for (int rg = 0; rg < 4; ++rg)
          mP[swz64(rs * 16 + lg * 4 + rg, nt * 16 + lr)] = (_Float16)p2[nt][rg];
      asm volatile("" ::: "memory");
      f32x4 oacc[4];
#pragma unroll
      for (int nt = 0; nt < 4; ++nt) oacc[nt] = zero4;
#pragma unroll
      for (int ks = 0; ks < 2; ++ks) {
        f16x8 afp = *(const f16x8*)&mP[swz64(rs * 16 + lr, ks * 32 + lg * 8)];
#pragma unroll
        for (int nt = 0; nt < 4; ++nt) {
          f16x8 bfv = *(const f16x8*)&mV[swz64(nt * 16 + lr, ks * 32 + lg * 8)];
          oacc[nt] = MFMA16(afp, bfv, oacc[nt]);
        }
      }
      asm volatile("" ::: "memory");
#pragma unroll
      for (int nt = 0; nt < 4; ++nt)
#pragma unroll
        for (int rg = 0; rg < 4; ++rg)
          mP[swz64(rs * 16 + lg * 4 + rg, nt * 16 + lr)] = (_Float16)oacc[nt][rg];
    }
    __syncthreads();
    {
      f16x8 bfC[2][4], afC[2][4];
#pragma unroll
      for (int rt = 0; rt < 4; ++rt)
        afC[0][rt] = *(const f16x8*)&sPO0[swz64(rt * 16 + lr, lg * 8)];
#pragma unroll
      for (int nt = 0; nt < 4; ++nt)
        bfC[0][nt] = *(const f16x8*)(wprojP + (size_t)(wid * 4 + nt) * 8192 +
                                     (size_t)(hp * 4) * 512 + lane * 8);
#pragma unroll
      for (int g = 0; g < 4; ++g) {
        if (g < 3) {
          int hn = (g + 1) >> 1, kn = (g + 1) & 1;
#pragma unroll
          for (int rt = 0; rt < 4; ++rt)
            afC[(g + 1) & 1][rt] = *(const f16x8*)&sPO0[hn * 4096 +
                swz64(rt * 16 + lr, kn * 32 + lg * 8)];
#pragma unroll
          for (int nt = 0; nt < 4; ++nt)
            bfC[(g + 1) & 1][nt] =
                *(const f16x8*)(wprojP + (size_t)(wid * 4 + nt) * 8192 +
                                (size_t)(hp * 4 + g + 1) * 512 + lane * 8);
        }
#pragma unroll
        for (int nt = 0; nt < 4; ++nt)
#pragma unroll
          for (int rt = 0; rt < 4; ++rt)
            accO[rt][nt] = MFMA16(afC[g & 1][rt], bfC[g & 1][nt], accO[rt][nt]);
      }
    }
  }
  __syncthreads();
  float bias_r[4];
#pragma unroll
  for (int nt = 0; nt < 4; ++nt) bias_r[nt] = bproj[wid * 64 + nt * 16 + lr];
  float* sEp = (float*)&sHeads[0][0][0];
  size_t base = (size_t)blockIdx.x * 32768;
#pragma unroll
  for (int half = 0; half < 2; ++half) {
#pragma unroll
    for (int rr = 0; rr < 2; ++rr) {
      int rt = half * 2 + rr;
#pragma unroll
      for (int nt = 0; nt < 4; ++nt)
#pragma unroll
        for (int rg = 0; rg < 4; ++rg) {
          int r = rr * 16 + lg * 4 + rg;
          int c = wid * 64 + nt * 16 + lr;
          sEp[r * 512 + (c ^ (((r >> 2) & 1) << 4))] = accO[rt][nt][rg] + bias_r[nt];
        }
    }
    __syncthreads();
#pragma unroll
    for (int j = 0; j < 8; ++j) {
      int f4 = tid + j * 512;
      int r = f4 >> 7;
      int c0 = (f4 & 127) << 2;
      float4 v = *(const float4*)&sEp[r * 512 + (c0 ^ (((r >> 2) & 1) << 4))];
      *(float4*)&out[base + (size_t)(half * 32 + r) * 512 + c0] = v;
    }
    if (half == 0) __syncthreads();
  }
}

extern "C" void kernel_launch(void* const* d_in, const int* in_sizes, int n_in,
                              void* d_out, int out_size, void* d_ws, size_t ws_size,
                              hipStream_t stream) {
  const float* x = (const float*)d_in[0];
  const float* Wqkv = (const float*)d_in[1];
  const float* Wproj = (const float*)d_in[2];
  const float* bproj = (const float*)d_in[3];
  float* out = (float*)d_out;

  const size_t W1 = 786432, W2 = 262144, XN = 33554432;
  const size_t QN = 100663296, HN = 33554432;
  _Float16* wqkvP = (_Float16*)d_ws;
  _Float16* wprojP = wqkvP + W1;
  _Float16* xP = wprojP + W2;
  _Float16* qkvP = xP + XN;
  _Float16* hP = qkvP + QN;
  const size_t NEED = (W1 + W2 + XN + QN + HN) * 2;

  prep_weights<<<dim3(4096), dim3(256), 0, stream>>>(Wqkv, Wproj, wqkvP, wprojP);
  if (ws_size >= NEED) {
    prep_x<<<dim3(1024), dim3(512), 0, stream>>>(x, xP);
    // Q,K cols: A = Wqkv^T rows 0..1023 (4 row-tiles), B = tokens (256 tiles)
    gemm8<0><<<dim3(1024), dim3(512), 0, stream>>>(wqkvP, xP, qkvP, nullptr, nullptr, 4);
    // V cols: A = tokens (256 tiles), B = V weight rows (2 tiles)
    gemm8<1><<<dim3(512), dim3(512), 0, stream>>>(xP, wqkvP + (size_t)64 * 8192,
                                                  qkvP, nullptr, nullptr, 256);
    attn_win<<<dim3(1024), dim3(512), 0, stream>>>(qkvP, hP);
    // proj: A = Wproj^T rows (2 tiles), B = tokens (256 tiles)
    gemm8<2><<<dim3(512), dim3(512), 0, stream>>>(wprojP, hP, nullptr, out, bproj, 2);
  } else {
    attn_fused<<<dim3(1024), dim3(512), 0, stream>>>(x, wqkvP, wprojP, bproj, out);
  }
}